// Round 7
// baseline (254.464 us; speedup 1.0000x reference)
//
#include <hip/hip_runtime.h>
#include <math.h>

constexpr int N = 50000;   // nodes
constexpr int E = 800000;  // edges (without self-loops)
constexpr int F = 128;     // features / hidden
constexpr int G = 256;     // graphs
constexpr int T = 4;       // tasks

constexpr int BSH   = 5;                         // 32 nodes per bucket
constexpr int BNODES= 1 << BSH;
constexpr int NBUCK = (N + BNODES - 1) / BNODES; // 1563
constexpr int CHUNK = 2048;                      // edges per partition block (391 blocks)
constexpr int NCHUNK= (E + CHUNK - 1) / CHUNK;   // 391
constexpr int SSH   = 13;                        // src-slice shift: 8192-node slices

// k_pre block-range layout: wcast W1 | wcast W2 | zero pooled | histogram chunks
constexpr int WC_BLKS  = (F * F + 255) / 256;    // 64
constexpr int PRE_Z0   = 2 * WC_BLKS;            // 128
constexpr int PRE_ZB   = (G * F + 255) / 256;    // 128
constexpr int PRE_H0   = PRE_Z0 + PRE_ZB;        // 256
constexpr int PRE_BLKS = PRE_H0 + NCHUNK;        // 647

constexpr int GB1 = (N + 63) / 64;               // 782 gemm blocks
constexpr int GCB = GB1 + NBUCK;                 // fused gemm+colscan grid (2345)
constexpr int AGB = N / 16;                      // 3125 agg blocks (16 nodes/block)

typedef __attribute__((ext_vector_type(8))) short short8;
typedef __attribute__((ext_vector_type(4))) float floatx4;

// bf16 <-> fp32 helpers (RNE on pack; values are finite)
__device__ inline float bf2f(unsigned short u) {
    union { unsigned int i; float f; } v;
    v.i = ((unsigned int)u) << 16;
    return v.f;
}
__device__ inline unsigned short f2bf(float f) {
    union { float f; unsigned int i; } v;
    v.f = f;
    unsigned int r = v.i + 0x7FFF + ((v.i >> 16) & 1);
    return (unsigned short)(r >> 16);
}
__device__ inline unsigned int pack2bf(float a, float b) {
    return (unsigned int)f2bf(a) | ((unsigned int)f2bf(b) << 16);
}

// pack W (fp32) -> MFMA-B-fragment order, hi/lo bf16 split
__device__ inline void wcast_one(const float* __restrict__ W,
                                 unsigned short* __restrict__ Whi,
                                 unsigned short* __restrict__ Wlo, int i) {
    if (i >= F * F) return;
    int k = i >> 7, n = i & 127;
    float w = W[i];
    unsigned short hi = f2bf(w);
    unsigned short lo = f2bf(w - bf2f(hi));
    int s = k >> 5, q = (k >> 3) & 3, j = k & 7;
    int idx = (((s * 128 + n) * 4 + q) * 8) + j;
    Whi[idx] = hi;
    Wlo[idx] = lo;
}

// ------ fused preamble: wcast(W1/W2) + zero pooled + per-chunk LDS bucket histogram ------
__global__ __launch_bounds__(256) void k_pre(const float* __restrict__ W1, const float* __restrict__ W2,
                                             unsigned short* __restrict__ w1h, unsigned short* __restrict__ w1l,
                                             unsigned short* __restrict__ w2h, unsigned short* __restrict__ w2l,
                                             const int* __restrict__ dst, int* __restrict__ cnts,
                                             float* __restrict__ pooled) {
    __shared__ int h[NBUCK];
    int b = blockIdx.x, t = threadIdx.x;
    if (b < WC_BLKS) {
        wcast_one(W1, w1h, w1l, b * 256 + t);
    } else if (b < 2 * WC_BLKS) {
        wcast_one(W2, w2h, w2l, (b - WC_BLKS) * 256 + t);
    } else if (b < PRE_H0) {
        pooled[(b - PRE_Z0) * 256 + t] = 0.f;      // G*F = 32768 exactly
    } else {
        int chunk = b - PRE_H0;
        for (int i = t; i < NBUCK; i += 256) h[i] = 0;
        __syncthreads();
        int base = chunk * CHUNK;
        for (int i = t; i < CHUNK; i += 256) {
            int e = base + i;
            if (e < E) atomicAdd(&h[dst[e] >> BSH], 1);   // LDS atomic
        }
        __syncthreads();
        for (int i = t; i < NBUCK; i += 256) cnts[chunk * NBUCK + i] = h[i];
    }
}

// ---- deterministic partition: edges -> bucket-contiguous staging; scan folded in ----
__global__ __launch_bounds__(256) void k_fillb(const int* __restrict__ src,
                                               const int* __restrict__ dst,
                                               const int* __restrict__ cnts,
                                               const int* __restrict__ btot,
                                               int* __restrict__ bucketbase,
                                               unsigned int* __restrict__ staging) {
    __shared__ int bb[NBUCK + 1];
    __shared__ int part[256];
    __shared__ int lofs[NBUCK];
    int chunk = blockIdx.x, t = threadIdx.x;

    // ---- redundant per-block exclusive scan of btot -> bb (cheap: 6KB + 256-scan) ----
    constexpr int CH = (NBUCK + 255) / 256;   // 7
    int beg = t * CH;
    int end = (beg + CH < NBUCK) ? beg + CH : NBUCK;
    int tot[CH];
    int s = 0;
    for (int i = beg; i < end; ++i) {
        tot[i - beg] = btot[i];
        s += btot[i];
    }
    part[t] = s;
    __syncthreads();
    for (int off = 1; off < 256; off <<= 1) {
        int u = (t >= off) ? part[t - off] : 0;
        __syncthreads();
        part[t] += u;
        __syncthreads();
    }
    int run = (t == 0) ? 0 : part[t - 1];
    for (int i = beg; i < end; ++i) {
        bb[i] = run;
        run += tot[i - beg];
    }
    if (t == 255) bb[NBUCK] = part[255];      // == E
    __syncthreads();
    if (chunk == 0)
        for (int i = t; i <= NBUCK; i += 256) bucketbase[i] = bb[i];

    for (int i = t; i < NBUCK; i += 256)
        lofs[i] = bb[i] + cnts[chunk * NBUCK + i];
    __syncthreads();

    int base = chunk * CHUNK;
    for (int i = t; i < CHUNK; i += 256) {
        int e = base + i;
        if (e < E) {
            int d = dst[e];
            int pos = atomicAdd(&lofs[d >> BSH], 1);      // LDS atomic
            staging[pos] = (unsigned int)src[e] | ((unsigned int)(d & (BNODES - 1)) << 16);
        }
    }
}

// ---- pass B: per-bucket counting sort + dinv + in-place pre-scale of tmp16 rows ----
__global__ __launch_bounds__(256) void k_passB(const unsigned int* __restrict__ staging,
                                               const int* __restrict__ bucketbase,
                                               int* __restrict__ csr,
                                               int* __restrict__ rowstart,
                                               float* __restrict__ dinv,
                                               unsigned short* __restrict__ tmp16) {
    __shared__ unsigned int ent[1024];        // mean 512, 11-sigma safe
    __shared__ int h[BNODES * 8], off_a[BNODES * 8];   // (node, slice) bins
    __shared__ int nodebase[BNODES], ndeg[BNODES];
    __shared__ float sdinv[BNODES];
    int b = blockIdx.x, t = threadIdx.x;
    int jb = bucketbase[b], je = bucketbase[b + 1];
    int M = je - jb;
    if (M > 1024) M = 1024;
    if (t < BNODES * 8) h[t] = 0;
    __syncthreads();

    for (int i = t; i < M; i += 256) {
        unsigned int en = staging[jb + i];
        ent[i] = en;
        int key = (((en >> 16) & (BNODES - 1)) << 3) | ((en & 0xFFFFu) >> SSH);
        atomicAdd(&h[key], 1);
    }
    __syncthreads();

    if (t < BNODES) {
        int s = 0;
#pragma unroll
        for (int c = 0; c < 8; ++c) s += h[t * 8 + c];
        ndeg[t] = s;
    }
    __syncthreads();
    if (t == 0) {
        int run = jb;
        for (int k = 0; k < BNODES; ++k) {
            nodebase[k] = run;
            run += ndeg[k];
        }
    }
    __syncthreads();
    if (t < BNODES) {
        int run = nodebase[t];
#pragma unroll
        for (int c = 0; c < 8; ++c) {
            off_a[t * 8 + c] = run;
            run += h[t * 8 + c];
        }
        float dv = rsqrtf((float)(ndeg[t] + 1));   // +1 self-loop
        sdinv[t] = dv;
        int node = b * BNODES + t;
        if (node < N) {
            rowstart[node] = nodebase[t];
            dinv[node] = dv;
        }
    }
    if (b == 0 && t == 0) rowstart[N] = E;
    __syncthreads();

    for (int i = t; i < M; i += 256) {
        unsigned int en = ent[i];
        int key = (((en >> 16) & (BNODES - 1)) << 3) | ((en & 0xFFFFu) >> SSH);
        int loc = atomicAdd(&off_a[key], 1);
        csr[loc] = (int)(en & 0xFFFFu);
    }

    // ---- in-place scale: tmp16[row] *= dinv[row] for this bucket's 32 rows ----
    uint4* t4 = (uint4*)tmp16;
    for (int i = t; i < BNODES * 16; i += 256) {        // 512 uint4, 2 per thread
        int rl = i >> 4, qi = i & 15;
        int node = b * BNODES + rl;
        if (node < N) {
            float dv = sdinv[rl];
            uint4 u = t4[node * 16 + qi];
            uint4 o;
            o.x = pack2bf(bf2f((unsigned short)(u.x & 0xFFFFu)) * dv, bf2f((unsigned short)(u.x >> 16)) * dv);
            o.y = pack2bf(bf2f((unsigned short)(u.y & 0xFFFFu)) * dv, bf2f((unsigned short)(u.y >> 16)) * dv);
            o.z = pack2bf(bf2f((unsigned short)(u.z & 0xFFFFu)) * dv, bf2f((unsigned short)(u.z >> 16)) * dv);
            o.w = pack2bf(bf2f((unsigned short)(u.w & 0xFFFFu)) * dv, bf2f((unsigned short)(u.w >> 16)) * dv);
            t4[node * 16 + qi] = o;
        }
    }
}

// ---------------- MFMA GEMM body (64-row tile): C16 = A @ W (raw, no dinv) ----------------
template <bool ABF16>
__device__ __forceinline__ void gemm_body(const void* __restrict__ Ain,
                                          const unsigned short* __restrict__ Wph,
                                          const unsigned short* __restrict__ Wpl,
                                          unsigned short* __restrict__ C16,
                                          int row0, int tid,
                                          unsigned short* __restrict__ Albs) {
    if (ABF16) {
        const uint4* A8 = (const uint4*)Ain;
        for (int f = tid; f < 64 * 16; f += 256) {
            int r = f >> 4, kq = f & 15;
            int row = row0 + r;
            uint4 v = make_uint4(0u, 0u, 0u, 0u);
            if (row < N) v = A8[row * 16 + kq];
            *(uint4*)&Albs[r * 136 + kq * 8] = v;
        }
    } else {
        const float4* A4 = (const float4*)Ain;
        for (int f = tid; f < 64 * 32; f += 256) {
            int r = f >> 5, kq = f & 31;
            int row = row0 + r;
            float4 v = make_float4(0.f, 0.f, 0.f, 0.f);
            if (row < N) v = A4[row * 32 + kq];
            ushort4 o;
            o.x = f2bf(v.x); o.y = f2bf(v.y); o.z = f2bf(v.z); o.w = f2bf(v.w);
            *(ushort4*)&Albs[r * 136 + kq * 4] = o;
        }
    }
    __syncthreads();

    int wv = tid >> 6;
    int lane = tid & 63;
    int c16 = lane & 15;
    int q = lane >> 4;
    int m = wv * 16 + c16;

    floatx4 acc[8];
#pragma unroll
    for (int nt = 0; nt < 8; ++nt) acc[nt] = (floatx4){0.f, 0.f, 0.f, 0.f};

    const short8* WH = (const short8*)Wph;
    const short8* WL = (const short8*)Wpl;
#pragma unroll
    for (int s = 0; s < 4; ++s) {
        short8 a = *(const short8*)&Albs[m * 136 + s * 32 + q * 8];
        int wb = s * 512 + c16 * 4 + q;
#pragma unroll
        for (int nt = 0; nt < 8; ++nt) {
            acc[nt] = __builtin_amdgcn_mfma_f32_16x16x32_bf16(a, WH[wb + nt * 64], acc[nt], 0, 0, 0);
            acc[nt] = __builtin_amdgcn_mfma_f32_16x16x32_bf16(a, WL[wb + nt * 64], acc[nt], 0, 0, 0);
        }
    }

    int rbase = row0 + wv * 16 + q * 4;
#pragma unroll
    for (int r = 0; r < 4; ++r) {
        int row = rbase + r;
        if (row < N) {
#pragma unroll
            for (int nt = 0; nt < 8; ++nt)
                C16[row * 128 + nt * 16 + c16] = f2bf(acc[nt][r]);
        }
    }
}

// ------- fused: layer-1 GEMM (blocks < GB1) + parallel colscan (blocks >= GB1) -------
__global__ __launch_bounds__(256) void k_gemmcol(const float* __restrict__ x,
                                                 const unsigned short* __restrict__ w1h,
                                                 const unsigned short* __restrict__ w1l,
                                                 unsigned short* __restrict__ tmp16,
                                                 int* __restrict__ cnts,
                                                 int* __restrict__ btot) {
    __shared__ __align__(16) unsigned short Albs[64 * 136];
    int b = blockIdx.x, t = threadIdx.x;
    if (b < GB1) {
        gemm_body<false>(x, w1h, w1l, tmp16, b * 64, t, Albs);
        return;
    }
    // ---- colscan: one block per bucket, in-block scan over NCHUNK=391 values ----
    int j = b - GB1;
    int* part = (int*)Albs;
    int k0 = 2 * t, k1 = 2 * t + 1;
    int v0 = (k0 < NCHUNK) ? cnts[k0 * NBUCK + j] : 0;
    int v1 = (k1 < NCHUNK) ? cnts[k1 * NBUCK + j] : 0;
    int s = v0 + v1;
    part[t] = s;
    __syncthreads();
    for (int off = 1; off < 256; off <<= 1) {
        int u = (t >= off) ? part[t - off] : 0;
        __syncthreads();
        part[t] += u;
        __syncthreads();
    }
    int excl = part[t] - s;
    if (k0 < NCHUNK) cnts[k0 * NBUCK + j] = excl;
    if (k1 < NCHUNK) cnts[k1 * NBUCK + j] = excl + v0;
    if (t == 255) btot[j] = part[255];
}

// 8 bf16 (uint4) add into 8 fp32 accumulators (coefficient-free hot path)
__device__ inline void add8(const uint4& u, float* acc) {
    union { unsigned int i; float f; } a;
    a.i = u.x << 16;          acc[0] += a.f;
    a.i = u.x & 0xFFFF0000u;  acc[1] += a.f;
    a.i = u.y << 16;          acc[2] += a.f;
    a.i = u.y & 0xFFFF0000u;  acc[3] += a.f;
    a.i = u.z << 16;          acc[4] += a.f;
    a.i = u.z & 0xFFFF0000u;  acc[5] += a.f;
    a.i = u.w << 16;          acc[6] += a.f;
    a.i = u.w & 0xFFFF0000u;  acc[7] += a.f;
}

// 8 bf16 (uint4) fma into 8 fp32 accumulators (masked tail + pooling)
__device__ inline void fma8(const uint4& u, float c, float* acc) {
    union { unsigned int i; float f; } a;
    a.i = u.x << 16;          acc[0] = fmaf(a.f, c, acc[0]);
    a.i = u.x & 0xFFFF0000u;  acc[1] = fmaf(a.f, c, acc[1]);
    a.i = u.y << 16;          acc[2] = fmaf(a.f, c, acc[2]);
    a.i = u.y & 0xFFFF0000u;  acc[3] = fmaf(a.f, c, acc[3]);
    a.i = u.z << 16;          acc[4] = fmaf(a.f, c, acc[4]);
    a.i = u.z & 0xFFFF0000u;  acc[5] = fmaf(a.f, c, acc[5]);
    a.i = u.w << 16;          acc[6] = fmaf(a.f, c, acc[6]);
    a.i = u.w & 0xFFFF0000u;  acc[7] = fmaf(a.f, c, acc[7]);
}

// agg inner loop (round-5 proven form): 8-deep full chunks with next-chunk csr
// prefetch (branch-free body); one masked tail chunk. ~52 VGPR — TLP comes from
// node-split (2 groups/node), NOT deeper unroll (r6: 16-deep cost occupancy, -5%).
__device__ __forceinline__ void agg_loop(const uint4* __restrict__ t8l,  // t8 + lane
                                         const int* __restrict__ csr,
                                         int jb, int je, float* acc) {
    int n8 = (je - jb) >> 3;
    int j = jb;
    if (n8 > 0) {
        int e[8];
#pragma unroll
        for (int k = 0; k < 8; ++k) e[k] = csr[j + k];
        for (int c = 0; c < n8; ++c) {
            uint4 u[8];
#pragma unroll
            for (int k = 0; k < 8; ++k) u[k] = t8l[e[k] * 16];
            j += 8;
            if (c + 1 < n8) {
#pragma unroll
                for (int k = 0; k < 8; ++k) e[k] = csr[j + k];   // prefetch next chunk's indices
            }
#pragma unroll
            for (int k = 0; k < 8; ++k) add8(u[k], acc);
        }
    }
    if (j < je) {                       // masked tail (1..7 edges)
        int e[8];
        float msk[8];
#pragma unroll
        for (int k = 0; k < 8; ++k) {
            int idx = j + k;
            e[k] = csr[idx < je ? idx : je - 1];
            msk[k] = (idx < je) ? 1.0f : 0.0f;
        }
        uint4 u[8];
#pragma unroll
        for (int k = 0; k < 8; ++k) u[k] = t8l[e[k] * 16];
#pragma unroll
        for (int k = 0; k < 8; ++k) fma8(u[k], msk[k], acc);
    }
}

// ---- fused layer-1 agg + layer-2 GEMM: 512 threads, 16 nodes, 2 gather-groups/node ----
__global__ __launch_bounds__(512) void k_agg1gemm(const unsigned short* __restrict__ tmp16,
                                                  const int* __restrict__ csr,
                                                  const int* __restrict__ rowstart,
                                                  const float* __restrict__ dinv,
                                                  const float* __restrict__ bias,
                                                  const unsigned short* __restrict__ w2h,
                                                  const unsigned short* __restrict__ w2l,
                                                  unsigned short* __restrict__ tmp2) {
    __shared__ __align__(16) unsigned short Albs[16 * 136];
    __shared__ float pred[16][128];           // half-1 partial sums
    int tid = threadIdx.x;
    int row0 = blockIdx.x * 16;

    // ---- phase A: split aggregation ----
    {
        int group = tid >> 4;                 // 0..31
        int ns = group >> 1;                  // node slot 0..15
        int half = group & 1;
        int lane = tid & 15;
        int node = row0 + ns;
        const uint4* t8l = (const uint4*)tmp16 + lane;
        int jb = rowstart[node], je = rowstart[node + 1];
        int mid = jb + ((je - jb) >> 1);
        float acc[8] = {0.f, 0.f, 0.f, 0.f, 0.f, 0.f, 0.f, 0.f};
        if (half == 0) {
            add8(t8l[node * 16], acc);        // self-loop term
            agg_loop(t8l, csr, jb, mid, acc);
        } else {
            agg_loop(t8l, csr, mid, je, acc);
#pragma unroll
            for (int k = 0; k < 8; ++k) pred[ns][lane * 8 + k] = acc[k];
        }
        __syncthreads();
        if (half == 0) {
            float di = dinv[node];
            const float4* b4 = (const float4*)bias;
            float4 ba = b4[lane * 2], bb = b4[lane * 2 + 1];
#pragma unroll
            for (int k = 0; k < 8; ++k) acc[k] += pred[ns][lane * 8 + k];
            uint4 o;
            o.x = pack2bf(fmaxf(fmaf(acc[0], di, ba.x), 0.f), fmaxf(fmaf(acc[1], di, ba.y), 0.f));
            o.y = pack2bf(fmaxf(fmaf(acc[2], di, ba.z), 0.f), fmaxf(fmaf(acc[3], di, ba.w), 0.f));
            o.z = pack2bf(fmaxf(fmaf(acc[4], di, bb.x), 0.f), fmaxf(fmaf(acc[5], di, bb.y), 0.f));
            o.w = pack2bf(fmaxf(fmaf(acc[6], di, bb.z), 0.f), fmaxf(fmaf(acc[7], di, bb.w), 0.f));
            *(uint4*)&Albs[ns * 136 + lane * 8] = o;
        }
    }
    __syncthreads();

    // ---- phase B: 16-row MFMA gemm, 8 waves x 1 n-tile; output pre-scaled by dinv ----
    int wv = tid >> 6;                        // 0..7 == n-tile
    int lane = tid & 63;
    int c16 = lane & 15;
    int q = lane >> 4;

    floatx4 acc2 = (floatx4){0.f, 0.f, 0.f, 0.f};
    const short8* WH = (const short8*)w2h;
    const short8* WL = (const short8*)w2l;
#pragma unroll
    for (int s = 0; s < 4; ++s) {
        short8 a = *(const short8*)&Albs[c16 * 136 + s * 32 + q * 8];
        int wb = s * 512 + c16 * 4 + q;
        acc2 = __builtin_amdgcn_mfma_f32_16x16x32_bf16(a, WH[wb + wv * 64], acc2, 0, 0, 0);
        acc2 = __builtin_amdgcn_mfma_f32_16x16x32_bf16(a, WL[wb + wv * 64], acc2, 0, 0, 0);
    }

    int rbase = row0 + q * 4;
#pragma unroll
    for (int r = 0; r < 4; ++r) {
        int row = rbase + r;
        float dv = dinv[row];
        tmp2[row * 128 + wv * 16 + c16] = f2bf(acc2[r] * dv);
    }
}

// ---- layer-2 agg + fused pooling: 512 threads, 16 nodes, 2 gather-groups/node ----
__global__ __launch_bounds__(512) void k_agg(const unsigned short* __restrict__ tmp16,
                                             const int* __restrict__ csr,
                                             const int* __restrict__ rowstart,
                                             const float* __restrict__ dinv,
                                             const float* __restrict__ bias,
                                             const int* __restrict__ batch,
                                             float* __restrict__ pooled) {
    __shared__ float red[16][128];            // half-1 partials, then finished rows
    __shared__ int gid[16];
    int tid = threadIdx.x;
    int node0 = blockIdx.x * 16;              // AGB*16 == N exactly
    int group = tid >> 4, ns = group >> 1, half = group & 1, lane = tid & 15;
    int node = node0 + ns;
    const uint4* t8l = (const uint4*)tmp16 + lane;
    int jb = rowstart[node], je = rowstart[node + 1];
    int mid = jb + ((je - jb) >> 1);
    float acc[8] = {0.f, 0.f, 0.f, 0.f, 0.f, 0.f, 0.f, 0.f};
    if (half == 0) {
        add8(t8l[node * 16], acc);
        agg_loop(t8l, csr, jb, mid, acc);
    } else {
        agg_loop(t8l, csr, mid, je, acc);
#pragma unroll
        for (int k = 0; k < 8; ++k) red[ns][lane * 8 + k] = acc[k];
    }
    if (tid < 16) gid[tid] = batch[node0 + tid];
    __syncthreads();

    if (half == 0) {                          // combine halves + bias + relu (in place)
        float di = dinv[node];
        const float4* b4 = (const float4*)bias;
        float4 ba = b4[lane * 2], bb = b4[lane * 2 + 1];
        red[ns][lane * 8 + 0] = fmaxf(fmaf(acc[0] + red[ns][lane * 8 + 0], di, ba.x), 0.f);
        red[ns][lane * 8 + 1] = fmaxf(fmaf(acc[1] + red[ns][lane * 8 + 1], di, ba.y), 0.f);
        red[ns][lane * 8 + 2] = fmaxf(fmaf(acc[2] + red[ns][lane * 8 + 2], di, ba.z), 0.f);
        red[ns][lane * 8 + 3] = fmaxf(fmaf(acc[3] + red[ns][lane * 8 + 3], di, ba.w), 0.f);
        red[ns][lane * 8 + 4] = fmaxf(fmaf(acc[4] + red[ns][lane * 8 + 4], di, bb.x), 0.f);
        red[ns][lane * 8 + 5] = fmaxf(fmaf(acc[5] + red[ns][lane * 8 + 5], di, bb.y), 0.f);
        red[ns][lane * 8 + 6] = fmaxf(fmaf(acc[6] + red[ns][lane * 8 + 6], di, bb.z), 0.f);
        red[ns][lane * 8 + 7] = fmaxf(fmaf(acc[7] + red[ns][lane * 8 + 7], di, bb.w), 0.f);
    }
    __syncthreads();

    if (tid < 128) {                          // run-length reduce over sorted batch ids
        int f = tid;
        float run = 0.f;
        int g = gid[0];
        for (int r = 0; r < 16; ++r) {
            if (gid[r] != g) {
                atomicAdd(&pooled[g * 128 + f], run);
                run = 0.f;
                g = gid[r];
            }
            run += red[r][f];
        }
        atomicAdd(&pooled[g * 128 + f], run);
    }
}

// ---------------- slim pool-finish + fc + head: reads pooled sums only ----------------
__global__ __launch_bounds__(128) void k_poolhead(const float* __restrict__ pooled,
                                                  const int* __restrict__ batch,
                                                  const float* __restrict__ Wfc,
                                                  const float* __restrict__ bfc,
                                                  const float* __restrict__ Wh,
                                                  const float* __restrict__ bh,
                                                  float* __restrict__ out) {
    __shared__ float p[128];
    __shared__ float zs[128];
    int g = blockIdx.x, t = threadIdx.x;

    int lo = 0, hi = N;                       // lower_bound(g)
    while (lo < hi) { int m = (lo + hi) >> 1; if (batch[m] < g) lo = m + 1; else hi = m; }
    int lo1 = lo, hi1 = N;                    // lower_bound(g+1)
    while (lo1 < hi1) { int m = (lo1 + hi1) >> 1; if (batch[m] < g + 1) lo1 = m + 1; else hi1 = m; }
    int cnt = lo1 - lo;
    float inv = 1.0f / (float)((cnt > 1) ? cnt : 1);

    p[t] = pooled[g * 128 + t] * inv;
    __syncthreads();

    float a = bfc[t];
    for (int k = 0; k < F; ++k) a = fmaf(p[k], Wfc[k * F + t], a);
    zs[t] = fmaxf(a, 0.f);
    __syncthreads();

    if (t < T * 2) {
        int task = t >> 1, c = t & 1;
        float a2 = bh[task * 2 + c];
        const float* wr = &Wh[task * F * 2 + c];
        for (int h = 0; h < F; ++h) a2 = fmaf(zs[h], wr[h * 2], a2);
        out[task * (G * 2) + g * 2 + c] = a2;
    }
}

extern "C" void kernel_launch(void* const* d_in, const int* in_sizes, int n_in,
                              void* d_out, int out_size, void* d_ws, size_t ws_size,
                              hipStream_t stream) {
    const float* x    = (const float*)d_in[0];
    const int*   ei   = (const int*)d_in[1];      // [2,E]: row0=src, row1=dst
    const int*   batch= (const int*)d_in[2];
    const float* W1   = (const float*)d_in[3];
    const float* b1   = (const float*)d_in[4];
    const float* W2   = (const float*)d_in[5];
    const float* b2   = (const float*)d_in[6];
    const float* Wfc  = (const float*)d_in[7];
    const float* bfc  = (const float*)d_in[8];
    const float* Wh   = (const float*)d_in[9];
    const float* bh   = (const float*)d_in[10];
    float* out = (float*)d_out;

    const int* srcp = ei;
    const int* dstp = ei + E;

    char* w = (char*)d_ws;
    auto alloc = [&](size_t bytes) {
        char* p = w;
        w += (bytes + 255) & ~(size_t)255;
        return p;
    };
    unsigned short* tmp16 = (unsigned short*)alloc((size_t)N * F * 2);
    unsigned short* tmp2  = (unsigned short*)alloc((size_t)N * F * 2);
    int*   csr      = (int*)  alloc((size_t)E * 4);
    unsigned int* staging = (unsigned int*)alloc((size_t)E * 4);
    int*   cnts     = (int*)  alloc((size_t)NCHUNK * NBUCK * 4);
    int*   btot     = (int*)  alloc((size_t)NBUCK * 4);
    int*   bucketbase=(int*)  alloc((size_t)(NBUCK + 1) * 4);
    int*   rowstart = (int*)  alloc((size_t)(N + 1) * 4);
    float* dinv     = (float*)alloc((size_t)N * 4);
    float* pooled   = (float*)alloc((size_t)G * F * 4);
    unsigned short* w1h = (unsigned short*)alloc((size_t)F * F * 2);
    unsigned short* w1l = (unsigned short*)alloc((size_t)F * F * 2);
    unsigned short* w2h = (unsigned short*)alloc((size_t)F * F * 2);
    unsigned short* w2l = (unsigned short*)alloc((size_t)F * F * 2);

    // fused preamble: wcast W1/W2 + zero pooled + per-chunk LDS bucket histogram
    k_pre<<<PRE_BLKS, 256, 0, stream>>>(W1, W2, w1h, w1l, w2h, w2l, dstp, cnts, pooled);

    // fused: layer-1 GEMM (raw output) + parallel colscan
    k_gemmcol<<<GCB, 256, 0, stream>>>(x, w1h, w1l, tmp16, cnts, btot);

    // partition: fillb (with folded bucketscan) -> passB (computes dinv + pre-scales tmp16)
    k_fillb<<<NCHUNK, 256, 0, stream>>>(srcp, dstp, cnts, btot, bucketbase, staging);
    k_passB<<<NBUCK, 256, 0, stream>>>(staging, bucketbase, csr, rowstart, dinv, tmp16);

    // fused: layer-1 aggregation (node-split, 2 groups/node) + layer-2 GEMM
    k_agg1gemm<<<AGB, 512, 0, stream>>>(tmp16, csr, rowstart, dinv, b1, w2h, w2l, tmp2);

    // layer-2 aggregation (node-split) + fused pooling (atomics into pooled)
    k_agg<<<AGB, 512, 0, stream>>>(tmp2, csr, rowstart, dinv, b2, batch, pooled);

    // slim pool-finish + fc + head
    k_poolhead<<<G, 128, 0, stream>>>(pooled, batch, Wfc, bfc, Wh, bh, out);
}

// Round 8
// 207.475 us; speedup vs baseline: 1.2265x; 1.2265x over previous
//
#include <hip/hip_runtime.h>
#include <math.h>

constexpr int N = 50000;   // nodes
constexpr int E = 800000;  // edges (without self-loops)
constexpr int F = 128;     // features / hidden
constexpr int G = 256;     // graphs
constexpr int T = 4;       // tasks

constexpr int BSH   = 5;                         // 32 nodes per bucket
constexpr int BNODES= 1 << BSH;
constexpr int NBUCK = (N + BNODES - 1) / BNODES; // 1563
constexpr int CHUNK = 4096;                      // edges per partition block (196 blocks)
constexpr int NCHUNK= (E + CHUNK - 1) / CHUNK;   // 196
constexpr int SSH   = 13;                        // src-slice shift: 8192-node slices

// k_pre block-range layout: wcast W1 | wcast W2 | zero pooled | histogram chunks
constexpr int WC_BLKS  = (F * F + 255) / 256;    // 64
constexpr int PRE_Z0   = 2 * WC_BLKS;            // 128
constexpr int PRE_ZB   = (G * F + 255) / 256;    // 128
constexpr int PRE_H0   = PRE_Z0 + PRE_ZB;        // 256
constexpr int PRE_BLKS = PRE_H0 + NCHUNK;        // 452

constexpr int GB1 = (N + 63) / 64;               // 782 gemm blocks
constexpr int GFB = GB1 + NCHUNK;                // fused gemm+fillb grid (978)
constexpr int AGB = N / 16;                      // 3125 agg blocks (16 nodes/block)

typedef __attribute__((ext_vector_type(8))) short short8;
typedef __attribute__((ext_vector_type(4))) float floatx4;

// bf16 <-> fp32 helpers (RNE on pack; values are finite)
__device__ inline float bf2f(unsigned short u) {
    union { unsigned int i; float f; } v;
    v.i = ((unsigned int)u) << 16;
    return v.f;
}
__device__ inline unsigned short f2bf(float f) {
    union { float f; unsigned int i; } v;
    v.f = f;
    unsigned int r = v.i + 0x7FFF + ((v.i >> 16) & 1);
    return (unsigned short)(r >> 16);
}
__device__ inline unsigned int pack2bf(float a, float b) {
    return (unsigned int)f2bf(a) | ((unsigned int)f2bf(b) << 16);
}

// pack W (fp32) -> MFMA-B-fragment order, hi/lo bf16 split
__device__ inline void wcast_one(const float* __restrict__ W,
                                 unsigned short* __restrict__ Whi,
                                 unsigned short* __restrict__ Wlo, int i) {
    if (i >= F * F) return;
    int k = i >> 7, n = i & 127;
    float w = W[i];
    unsigned short hi = f2bf(w);
    unsigned short lo = f2bf(w - bf2f(hi));
    int s = k >> 5, q = (k >> 3) & 3, j = k & 7;
    int idx = (((s * 128 + n) * 4 + q) * 8) + j;
    Whi[idx] = hi;
    Wlo[idx] = lo;
}

// ------ fused preamble: wcast(W1/W2) + zero pooled + per-chunk LDS bucket histogram ------
__global__ __launch_bounds__(256) void k_pre(const float* __restrict__ W1, const float* __restrict__ W2,
                                             unsigned short* __restrict__ w1h, unsigned short* __restrict__ w1l,
                                             unsigned short* __restrict__ w2h, unsigned short* __restrict__ w2l,
                                             const int* __restrict__ dst, int* __restrict__ cnts,
                                             float* __restrict__ pooled) {
    __shared__ int h[NBUCK];
    int b = blockIdx.x, t = threadIdx.x;
    if (b < WC_BLKS) {
        wcast_one(W1, w1h, w1l, b * 256 + t);
    } else if (b < 2 * WC_BLKS) {
        wcast_one(W2, w2h, w2l, (b - WC_BLKS) * 256 + t);
    } else if (b < PRE_H0) {
        pooled[(b - PRE_Z0) * 256 + t] = 0.f;      // G*F = 32768 exactly
    } else {
        int chunk = b - PRE_H0;
        for (int i = t; i < NBUCK; i += 256) h[i] = 0;
        __syncthreads();
        int base = chunk * CHUNK;
        for (int i = t; i < CHUNK; i += 256) {
            int e = base + i;
            if (e < E) atomicAdd(&h[dst[e] >> BSH], 1);   // LDS atomic
        }
        __syncthreads();
        for (int i = t; i < NBUCK; i += 256) cnts[chunk * NBUCK + i] = h[i];
    }
}

// ---- parallel colscan: one block per bucket, in-block scan over NCHUNK=196 values ----
__global__ __launch_bounds__(256) void k_colscan(int* __restrict__ cnts, int* __restrict__ btot) {
    __shared__ int part[256];
    int j = blockIdx.x, t = threadIdx.x;
    int k0 = 2 * t, k1 = 2 * t + 1;
    int v0 = (k0 < NCHUNK) ? cnts[k0 * NBUCK + j] : 0;
    int v1 = (k1 < NCHUNK) ? cnts[k1 * NBUCK + j] : 0;
    int s = v0 + v1;
    part[t] = s;
    __syncthreads();
    for (int off = 1; off < 256; off <<= 1) {
        int u = (t >= off) ? part[t - off] : 0;
        __syncthreads();
        part[t] += u;
        __syncthreads();
    }
    int excl = part[t] - s;
    if (k0 < NCHUNK) cnts[k0 * NBUCK + j] = excl;
    if (k1 < NCHUNK) cnts[k1 * NBUCK + j] = excl + v0;
    if (t == 255) btot[j] = part[255];
}

// ---------------- MFMA GEMM body (64-row tile): C16 = A @ W (raw, no dinv) ----------------
template <bool ABF16>
__device__ __forceinline__ void gemm_body(const void* __restrict__ Ain,
                                          const unsigned short* __restrict__ Wph,
                                          const unsigned short* __restrict__ Wpl,
                                          unsigned short* __restrict__ C16,
                                          int row0, int tid,
                                          unsigned short* __restrict__ Albs) {
    if (ABF16) {
        const uint4* A8 = (const uint4*)Ain;
        for (int f = tid; f < 64 * 16; f += 256) {
            int r = f >> 4, kq = f & 15;
            int row = row0 + r;
            uint4 v = make_uint4(0u, 0u, 0u, 0u);
            if (row < N) v = A8[row * 16 + kq];
            *(uint4*)&Albs[r * 136 + kq * 8] = v;
        }
    } else {
        const float4* A4 = (const float4*)Ain;
        for (int f = tid; f < 64 * 32; f += 256) {
            int r = f >> 5, kq = f & 31;
            int row = row0 + r;
            float4 v = make_float4(0.f, 0.f, 0.f, 0.f);
            if (row < N) v = A4[row * 32 + kq];
            ushort4 o;
            o.x = f2bf(v.x); o.y = f2bf(v.y); o.z = f2bf(v.z); o.w = f2bf(v.w);
            *(ushort4*)&Albs[r * 136 + kq * 4] = o;
        }
    }
    __syncthreads();

    int wv = tid >> 6;
    int lane = tid & 63;
    int c16 = lane & 15;
    int q = lane >> 4;
    int m = wv * 16 + c16;

    floatx4 acc[8];
#pragma unroll
    for (int nt = 0; nt < 8; ++nt) acc[nt] = (floatx4){0.f, 0.f, 0.f, 0.f};

    const short8* WH = (const short8*)Wph;
    const short8* WL = (const short8*)Wpl;
#pragma unroll
    for (int s = 0; s < 4; ++s) {
        short8 a = *(const short8*)&Albs[m * 136 + s * 32 + q * 8];
        int wb = s * 512 + c16 * 4 + q;
#pragma unroll
        for (int nt = 0; nt < 8; ++nt) {
            acc[nt] = __builtin_amdgcn_mfma_f32_16x16x32_bf16(a, WH[wb + nt * 64], acc[nt], 0, 0, 0);
            acc[nt] = __builtin_amdgcn_mfma_f32_16x16x32_bf16(a, WL[wb + nt * 64], acc[nt], 0, 0, 0);
        }
    }

    int rbase = row0 + wv * 16 + q * 4;
#pragma unroll
    for (int r = 0; r < 4; ++r) {
        int row = rbase + r;
        if (row < N) {
#pragma unroll
            for (int nt = 0; nt < 8; ++nt)
                C16[row * 128 + nt * 16 + c16] = f2bf(acc[nt][r]);
        }
    }
}

// ------- fused: layer-1 GEMM (blocks < GB1) + fillb partition (blocks >= GB1) -------
// fillb needs only k_colscan's output; it rides free under the ~30us GEMM.
__global__ __launch_bounds__(256) void k_gemmfill(const float* __restrict__ x,
                                                  const unsigned short* __restrict__ w1h,
                                                  const unsigned short* __restrict__ w1l,
                                                  unsigned short* __restrict__ tmp16,
                                                  const int* __restrict__ src,
                                                  const int* __restrict__ dst,
                                                  const int* __restrict__ cnts,
                                                  const int* __restrict__ btot,
                                                  int* __restrict__ bucketbase,
                                                  unsigned int* __restrict__ staging) {
    __shared__ __align__(16) char smem[64 * 136 * 2];   // 17408 B, unioned per branch
    int b = blockIdx.x, t = threadIdx.x;
    if (b < GB1) {
        gemm_body<false>(x, w1h, w1l, tmp16, b * 64, t, (unsigned short*)smem);
        return;
    }
    // ---- fillb: deterministic partition into bucket-contiguous staging ----
    int* bb   = (int*)smem;                   // NBUCK+1 = 1564
    int* part = bb + (NBUCK + 1);             // 256
    int* lofs = part + 256;                   // NBUCK = 1563  (total 13532 B <= 17408)
    int chunk = b - GB1;

    // redundant per-block exclusive scan of btot -> bb
    constexpr int CH = (NBUCK + 255) / 256;   // 7
    int beg = t * CH;
    int end = (beg + CH < NBUCK) ? beg + CH : NBUCK;
    int tot[CH];
    int s = 0;
    for (int i = beg; i < end; ++i) {
        tot[i - beg] = btot[i];
        s += btot[i];
    }
    part[t] = s;
    __syncthreads();
    for (int off = 1; off < 256; off <<= 1) {
        int u = (t >= off) ? part[t - off] : 0;
        __syncthreads();
        part[t] += u;
        __syncthreads();
    }
    int run = (t == 0) ? 0 : part[t - 1];
    for (int i = beg; i < end; ++i) {
        bb[i] = run;
        run += tot[i - beg];
    }
    if (t == 255) bb[NBUCK] = part[255];      // == E
    __syncthreads();
    if (chunk == 0)
        for (int i = t; i <= NBUCK; i += 256) bucketbase[i] = bb[i];

    for (int i = t; i < NBUCK; i += 256)
        lofs[i] = bb[i] + cnts[chunk * NBUCK + i];
    __syncthreads();

    int base = chunk * CHUNK;
    for (int i = t; i < CHUNK; i += 256) {
        int e = base + i;
        if (e < E) {
            int d = dst[e];
            int pos = atomicAdd(&lofs[d >> BSH], 1);      // LDS atomic
            staging[pos] = (unsigned int)src[e] | ((unsigned int)(d & (BNODES - 1)) << 16);
        }
    }
}

// ---- pass B: per-bucket counting sort + dinv + in-place pre-scale of tmp16 rows ----
__global__ __launch_bounds__(256) void k_passB(const unsigned int* __restrict__ staging,
                                               const int* __restrict__ bucketbase,
                                               int* __restrict__ csr,
                                               int* __restrict__ rowstart,
                                               float* __restrict__ dinv,
                                               unsigned short* __restrict__ tmp16) {
    __shared__ unsigned int ent[1024];        // mean 512, 11-sigma safe
    __shared__ int h[BNODES * 8], off_a[BNODES * 8];   // (node, slice) bins
    __shared__ int nodebase[BNODES], ndeg[BNODES];
    __shared__ float sdinv[BNODES];
    int b = blockIdx.x, t = threadIdx.x;
    int jb = bucketbase[b], je = bucketbase[b + 1];
    int M = je - jb;
    if (M > 1024) M = 1024;
    if (t < BNODES * 8) h[t] = 0;
    __syncthreads();

    for (int i = t; i < M; i += 256) {
        unsigned int en = staging[jb + i];
        ent[i] = en;
        int key = (((en >> 16) & (BNODES - 1)) << 3) | ((en & 0xFFFFu) >> SSH);
        atomicAdd(&h[key], 1);
    }
    __syncthreads();

    if (t < BNODES) {
        int s = 0;
#pragma unroll
        for (int c = 0; c < 8; ++c) s += h[t * 8 + c];
        ndeg[t] = s;
    }
    __syncthreads();
    if (t == 0) {
        int run = jb;
        for (int k = 0; k < BNODES; ++k) {
            nodebase[k] = run;
            run += ndeg[k];
        }
    }
    __syncthreads();
    if (t < BNODES) {
        int run = nodebase[t];
#pragma unroll
        for (int c = 0; c < 8; ++c) {
            off_a[t * 8 + c] = run;
            run += h[t * 8 + c];
        }
        float dv = rsqrtf((float)(ndeg[t] + 1));   // +1 self-loop
        sdinv[t] = dv;
        int node = b * BNODES + t;
        if (node < N) {
            rowstart[node] = nodebase[t];
            dinv[node] = dv;
        }
    }
    if (b == 0 && t == 0) rowstart[N] = E;
    __syncthreads();

    for (int i = t; i < M; i += 256) {
        unsigned int en = ent[i];
        int key = (((en >> 16) & (BNODES - 1)) << 3) | ((en & 0xFFFFu) >> SSH);
        int loc = atomicAdd(&off_a[key], 1);
        csr[loc] = (int)(en & 0xFFFFu);
    }

    // ---- in-place scale: tmp16[row] *= dinv[row] for this bucket's 32 rows ----
    uint4* t4 = (uint4*)tmp16;
    for (int i = t; i < BNODES * 16; i += 256) {        // 512 uint4, 2 per thread
        int rl = i >> 4, qi = i & 15;
        int node = b * BNODES + rl;
        if (node < N) {
            float dv = sdinv[rl];
            uint4 u = t4[node * 16 + qi];
            uint4 o;
            o.x = pack2bf(bf2f((unsigned short)(u.x & 0xFFFFu)) * dv, bf2f((unsigned short)(u.x >> 16)) * dv);
            o.y = pack2bf(bf2f((unsigned short)(u.y & 0xFFFFu)) * dv, bf2f((unsigned short)(u.y >> 16)) * dv);
            o.z = pack2bf(bf2f((unsigned short)(u.z & 0xFFFFu)) * dv, bf2f((unsigned short)(u.z >> 16)) * dv);
            o.w = pack2bf(bf2f((unsigned short)(u.w & 0xFFFFu)) * dv, bf2f((unsigned short)(u.w >> 16)) * dv);
            t4[node * 16 + qi] = o;
        }
    }
}

// 8 bf16 (uint4) add into 8 fp32 accumulators (coefficient-free hot path)
__device__ inline void add8(const uint4& u, float* acc) {
    union { unsigned int i; float f; } a;
    a.i = u.x << 16;          acc[0] += a.f;
    a.i = u.x & 0xFFFF0000u;  acc[1] += a.f;
    a.i = u.y << 16;          acc[2] += a.f;
    a.i = u.y & 0xFFFF0000u;  acc[3] += a.f;
    a.i = u.z << 16;          acc[4] += a.f;
    a.i = u.z & 0xFFFF0000u;  acc[5] += a.f;
    a.i = u.w << 16;          acc[6] += a.f;
    a.i = u.w & 0xFFFF0000u;  acc[7] += a.f;
}

// 8 bf16 (uint4) fma into 8 fp32 accumulators (masked tail + pooling)
__device__ inline void fma8(const uint4& u, float c, float* acc) {
    union { unsigned int i; float f; } a;
    a.i = u.x << 16;          acc[0] = fmaf(a.f, c, acc[0]);
    a.i = u.x & 0xFFFF0000u;  acc[1] = fmaf(a.f, c, acc[1]);
    a.i = u.y << 16;          acc[2] = fmaf(a.f, c, acc[2]);
    a.i = u.y & 0xFFFF0000u;  acc[3] = fmaf(a.f, c, acc[3]);
    a.i = u.z << 16;          acc[4] = fmaf(a.f, c, acc[4]);
    a.i = u.z & 0xFFFF0000u;  acc[5] = fmaf(a.f, c, acc[5]);
    a.i = u.w << 16;          acc[6] = fmaf(a.f, c, acc[6]);
    a.i = u.w & 0xFFFF0000u;  acc[7] = fmaf(a.f, c, acc[7]);
}

// agg inner loop (round-5 proven form): 8-deep full chunks with next-chunk csr
// prefetch; one masked tail. r6 (16-deep ILP) and r7 (node-split TLP) both
// regressed — the gather is at the memory-system's random-access service limit.
__device__ __forceinline__ void agg_loop(const uint4* __restrict__ t8l,  // t8 + lane
                                         const int* __restrict__ csr,
                                         int jb, int je, float* acc) {
    int n8 = (je - jb) >> 3;
    int j = jb;
    if (n8 > 0) {
        int e[8];
#pragma unroll
        for (int k = 0; k < 8; ++k) e[k] = csr[j + k];
        for (int c = 0; c < n8; ++c) {
            uint4 u[8];
#pragma unroll
            for (int k = 0; k < 8; ++k) u[k] = t8l[e[k] * 16];
            j += 8;
            if (c + 1 < n8) {
#pragma unroll
                for (int k = 0; k < 8; ++k) e[k] = csr[j + k];   // prefetch next chunk's indices
            }
#pragma unroll
            for (int k = 0; k < 8; ++k) add8(u[k], acc);
        }
    }
    if (j < je) {                       // masked tail (1..7 edges)
        int e[8];
        float msk[8];
#pragma unroll
        for (int k = 0; k < 8; ++k) {
            int idx = j + k;
            e[k] = csr[idx < je ? idx : je - 1];
            msk[k] = (idx < je) ? 1.0f : 0.0f;
        }
        uint4 u[8];
#pragma unroll
        for (int k = 0; k < 8; ++k) u[k] = t8l[e[k] * 16];
#pragma unroll
        for (int k = 0; k < 8; ++k) fma8(u[k], msk[k], acc);
    }
}

// ---------------- fused layer-1 agg + layer-2 GEMM (16 nodes/block) ----------------
__global__ __launch_bounds__(256) void k_agg1gemm(const unsigned short* __restrict__ tmp16,
                                                  const int* __restrict__ csr,
                                                  const int* __restrict__ rowstart,
                                                  const float* __restrict__ dinv,
                                                  const float* __restrict__ bias,
                                                  const unsigned short* __restrict__ w2h,
                                                  const unsigned short* __restrict__ w2l,
                                                  unsigned short* __restrict__ tmp2) {
    __shared__ __align__(16) unsigned short Albs[16 * 136];
    int tid = threadIdx.x;
    int row0 = blockIdx.x * 16;

    // ---- phase A: aggregation (h1 = relu(dinv_d * sum(tmp16[s]) + b1); tmp16 pre-scaled) ----
    {
        int node = row0 + (tid >> 4);
        int lane = tid & 15;
        const uint4* t8l = (const uint4*)tmp16 + lane;
        float acc[8] = {0.f, 0.f, 0.f, 0.f, 0.f, 0.f, 0.f, 0.f};
        add8(t8l[node * 16], acc);                       // self-loop term
        agg_loop(t8l, csr, rowstart[node], rowstart[node + 1], acc);

        float di = dinv[node];
        const float4* b4 = (const float4*)bias;
        float4 ba = b4[lane * 2], bb = b4[lane * 2 + 1];
        uint4 o;
        o.x = pack2bf(fmaxf(fmaf(acc[0], di, ba.x), 0.f), fmaxf(fmaf(acc[1], di, ba.y), 0.f));
        o.y = pack2bf(fmaxf(fmaf(acc[2], di, ba.z), 0.f), fmaxf(fmaf(acc[3], di, ba.w), 0.f));
        o.z = pack2bf(fmaxf(fmaf(acc[4], di, bb.x), 0.f), fmaxf(fmaf(acc[5], di, bb.y), 0.f));
        o.w = pack2bf(fmaxf(fmaf(acc[6], di, bb.z), 0.f), fmaxf(fmaf(acc[7], di, bb.w), 0.f));
        *(uint4*)&Albs[(tid >> 4) * 136 + lane * 8] = o;
    }
    __syncthreads();

    // ---- phase B: 16-row MFMA gemm, 4 waves x 2 n-tiles; output pre-scaled by dinv ----
    int wv = tid >> 6;
    int lane = tid & 63;
    int c16 = lane & 15;
    int q = lane >> 4;

    floatx4 acc[2];
    acc[0] = (floatx4){0.f, 0.f, 0.f, 0.f};
    acc[1] = (floatx4){0.f, 0.f, 0.f, 0.f};

    const short8* WH = (const short8*)w2h;
    const short8* WL = (const short8*)w2l;
#pragma unroll
    for (int s = 0; s < 4; ++s) {
        short8 a = *(const short8*)&Albs[c16 * 136 + s * 32 + q * 8];
        int wb = s * 512 + c16 * 4 + q;
#pragma unroll
        for (int i = 0; i < 2; ++i) {
            int nt = wv * 2 + i;
            acc[i] = __builtin_amdgcn_mfma_f32_16x16x32_bf16(a, WH[wb + nt * 64], acc[i], 0, 0, 0);
            acc[i] = __builtin_amdgcn_mfma_f32_16x16x32_bf16(a, WL[wb + nt * 64], acc[i], 0, 0, 0);
        }
    }

    int rbase = row0 + q * 4;
#pragma unroll
    for (int r = 0; r < 4; ++r) {
        int row = rbase + r;
        float dv = dinv[row];
#pragma unroll
        for (int i = 0; i < 2; ++i) {
            int nt = wv * 2 + i;
            tmp2[row * 128 + nt * 16 + c16] = f2bf(acc[i][r] * dv);
        }
    }
}

// ------- layer-2 aggregation + fused pooling (batch sorted -> LDS run-reduce + atomics) -------
__global__ __launch_bounds__(256) void k_agg(const unsigned short* __restrict__ tmp16,
                                             const int* __restrict__ csr,
                                             const int* __restrict__ rowstart,
                                             const float* __restrict__ dinv,
                                             const float* __restrict__ bias,
                                             const int* __restrict__ batch,
                                             float* __restrict__ pooled) {
    __shared__ float red[16][128];
    __shared__ int gid[16];
    int tid = threadIdx.x;
    int node0 = blockIdx.x * 16;              // AGB*16 == N exactly
    int ns = tid >> 4, lane = tid & 15;
    int node = node0 + ns;
    const uint4* t8l = (const uint4*)tmp16 + lane;
    float acc[8] = {0.f, 0.f, 0.f, 0.f, 0.f, 0.f, 0.f, 0.f};
    add8(t8l[node * 16], acc);
    agg_loop(t8l, csr, rowstart[node], rowstart[node + 1], acc);

    float di = dinv[node];
    const float4* b4 = (const float4*)bias;
    float4 ba = b4[lane * 2], bb = b4[lane * 2 + 1];
    red[ns][lane * 8 + 0] = fmaxf(fmaf(acc[0], di, ba.x), 0.f);
    red[ns][lane * 8 + 1] = fmaxf(fmaf(acc[1], di, ba.y), 0.f);
    red[ns][lane * 8 + 2] = fmaxf(fmaf(acc[2], di, ba.z), 0.f);
    red[ns][lane * 8 + 3] = fmaxf(fmaf(acc[3], di, ba.w), 0.f);
    red[ns][lane * 8 + 4] = fmaxf(fmaf(acc[4], di, bb.x), 0.f);
    red[ns][lane * 8 + 5] = fmaxf(fmaf(acc[5], di, bb.y), 0.f);
    red[ns][lane * 8 + 6] = fmaxf(fmaf(acc[6], di, bb.z), 0.f);
    red[ns][lane * 8 + 7] = fmaxf(fmaf(acc[7], di, bb.w), 0.f);
    if (tid < 16) gid[tid] = batch[node0 + tid];
    __syncthreads();

    if (tid < 128) {
        int f = tid;
        float run = 0.f;
        int g = gid[0];
        for (int r = 0; r < 16; ++r) {
            if (gid[r] != g) {
                atomicAdd(&pooled[g * 128 + f], run);
                run = 0.f;
                g = gid[r];
            }
            run += red[r][f];
        }
        atomicAdd(&pooled[g * 128 + f], run);
    }
}

// ---------------- slim pool-finish + fc + head: reads pooled sums only ----------------
__global__ __launch_bounds__(128) void k_poolhead(const float* __restrict__ pooled,
                                                  const int* __restrict__ batch,
                                                  const float* __restrict__ Wfc,
                                                  const float* __restrict__ bfc,
                                                  const float* __restrict__ Wh,
                                                  const float* __restrict__ bh,
                                                  float* __restrict__ out) {
    __shared__ float p[128];
    __shared__ float zs[128];
    int g = blockIdx.x, t = threadIdx.x;

    int lo = 0, hi = N;                       // lower_bound(g)
    while (lo < hi) { int m = (lo + hi) >> 1; if (batch[m] < g) lo = m + 1; else hi = m; }
    int lo1 = lo, hi1 = N;                    // lower_bound(g+1)
    while (lo1 < hi1) { int m = (lo1 + hi1) >> 1; if (batch[m] < g + 1) lo1 = m + 1; else hi1 = m; }
    int cnt = lo1 - lo;
    float inv = 1.0f / (float)((cnt > 1) ? cnt : 1);

    p[t] = pooled[g * 128 + t] * inv;
    __syncthreads();

    float a = bfc[t];
    for (int k = 0; k < F; ++k) a = fmaf(p[k], Wfc[k * F + t], a);
    zs[t] = fmaxf(a, 0.f);
    __syncthreads();

    if (t < T * 2) {
        int task = t >> 1, c = t & 1;
        float a2 = bh[task * 2 + c];
        const float* wr = &Wh[task * F * 2 + c];
        for (int h = 0; h < F; ++h) a2 = fmaf(zs[h], wr[h * 2], a2);
        out[task * (G * 2) + g * 2 + c] = a2;
    }
}

extern "C" void kernel_launch(void* const* d_in, const int* in_sizes, int n_in,
                              void* d_out, int out_size, void* d_ws, size_t ws_size,
                              hipStream_t stream) {
    const float* x    = (const float*)d_in[0];
    const int*   ei   = (const int*)d_in[1];      // [2,E]: row0=src, row1=dst
    const int*   batch= (const int*)d_in[2];
    const float* W1   = (const float*)d_in[3];
    const float* b1   = (const float*)d_in[4];
    const float* W2   = (const float*)d_in[5];
    const float* b2   = (const float*)d_in[6];
    const float* Wfc  = (const float*)d_in[7];
    const float* bfc  = (const float*)d_in[8];
    const float* Wh   = (const float*)d_in[9];
    const float* bh   = (const float*)d_in[10];
    float* out = (float*)d_out;

    const int* srcp = ei;
    const int* dstp = ei + E;

    char* w = (char*)d_ws;
    auto alloc = [&](size_t bytes) {
        char* p = w;
        w += (bytes + 255) & ~(size_t)255;
        return p;
    };
    unsigned short* tmp16 = (unsigned short*)alloc((size_t)N * F * 2);
    unsigned short* tmp2  = (unsigned short*)alloc((size_t)N * F * 2);
    int*   csr      = (int*)  alloc((size_t)E * 4);
    unsigned int* staging = (unsigned int*)alloc((size_t)E * 4);
    int*   cnts     = (int*)  alloc((size_t)NCHUNK * NBUCK * 4);
    int*   btot     = (int*)  alloc((size_t)NBUCK * 4);
    int*   bucketbase=(int*)  alloc((size_t)(NBUCK + 1) * 4);
    int*   rowstart = (int*)  alloc((size_t)(N + 1) * 4);
    float* dinv     = (float*)alloc((size_t)N * 4);
    float* pooled   = (float*)alloc((size_t)G * F * 4);
    unsigned short* w1h = (unsigned short*)alloc((size_t)F * F * 2);
    unsigned short* w1l = (unsigned short*)alloc((size_t)F * F * 2);
    unsigned short* w2h = (unsigned short*)alloc((size_t)F * F * 2);
    unsigned short* w2l = (unsigned short*)alloc((size_t)F * F * 2);

    // fused preamble: wcast W1/W2 + zero pooled + per-chunk LDS bucket histogram
    k_pre<<<PRE_BLKS, 256, 0, stream>>>(W1, W2, w1h, w1l, w2h, w2l, dstp, cnts, pooled);

    // parallel colscan (tiny): cnts -> within-bucket offsets + btot
    k_colscan<<<NBUCK, 256, 0, stream>>>(cnts, btot);

    // fused: layer-1 GEMM (raw output) + fillb partition (hidden under GEMM)
    k_gemmfill<<<GFB, 256, 0, stream>>>(x, w1h, w1l, tmp16, srcp, dstp, cnts, btot,
                                        bucketbase, staging);

    // passB: counting sort + dinv + in-place pre-scale of tmp16
    k_passB<<<NBUCK, 256, 0, stream>>>(staging, bucketbase, csr, rowstart, dinv, tmp16);

    // fused: layer-1 aggregation (coefficient-free gather) + layer-2 GEMM
    k_agg1gemm<<<AGB, 256, 0, stream>>>(tmp16, csr, rowstart, dinv, b1, w2h, w2l, tmp2);

    // layer-2 aggregation + fused pooling (atomics into pooled)
    k_agg<<<AGB, 256, 0, stream>>>(tmp2, csr, rowstart, dinv, b2, batch, pooled);

    // slim pool-finish + fc + head
    k_poolhead<<<G, 128, 0, stream>>>(pooled, batch, Wfc, bfc, Wh, bh, out);
}

// Round 9
// 207.025 us; speedup vs baseline: 1.2291x; 1.0022x over previous
//
#include <hip/hip_runtime.h>
#include <math.h>

constexpr int N = 50000;   // nodes
constexpr int E = 800000;  // edges (without self-loops)
constexpr int F = 128;     // features / hidden
constexpr int G = 256;     // graphs
constexpr int T = 4;       // tasks

constexpr int BSH   = 5;                         // 32 nodes per bucket
constexpr int BNODES= 1 << BSH;
constexpr int NBUCK = (N + BNODES - 1) / BNODES; // 1563
constexpr int CHUNK = 4096;                      // edges per partition block (196 blocks)
constexpr int NCHUNK= (E + CHUNK - 1) / CHUNK;   // 196
constexpr int SSH   = 13;                        // src-slice shift: 8192-node slices

// k_pre block-range layout: wcast W1 | wcast W2 | zero pooled | histogram chunks
constexpr int WC_BLKS  = (F * F + 255) / 256;    // 64
constexpr int PRE_Z0   = 2 * WC_BLKS;            // 128
constexpr int PRE_ZB   = (G * F + 255) / 256;    // 128
constexpr int PRE_H0   = PRE_Z0 + PRE_ZB;        // 256
constexpr int PRE_BLKS = PRE_H0 + NCHUNK;        // 452

constexpr int GB1 = (N + 63) / 64;               // 782 gemm blocks
constexpr int GFB = GB1 + NCHUNK;                // fused gemm+fillb grid (978)
constexpr int AGB = N / 16;                      // 3125 agg blocks (16 nodes/block)

typedef __attribute__((ext_vector_type(8))) short short8;
typedef __attribute__((ext_vector_type(4))) float floatx4;

// bf16 <-> fp32 helpers (RNE on pack; values are finite)
__device__ inline float bf2f(unsigned short u) {
    union { unsigned int i; float f; } v;
    v.i = ((unsigned int)u) << 16;
    return v.f;
}
__device__ inline unsigned short f2bf(float f) {
    union { float f; unsigned int i; } v;
    v.f = f;
    unsigned int r = v.i + 0x7FFF + ((v.i >> 16) & 1);
    return (unsigned short)(r >> 16);
}
__device__ inline unsigned int pack2bf(float a, float b) {
    return (unsigned int)f2bf(a) | ((unsigned int)f2bf(b) << 16);
}

// pack W (fp32) -> MFMA-B-fragment order, hi/lo bf16 split
__device__ inline void wcast_one(const float* __restrict__ W,
                                 unsigned short* __restrict__ Whi,
                                 unsigned short* __restrict__ Wlo, int i) {
    if (i >= F * F) return;
    int k = i >> 7, n = i & 127;
    float w = W[i];
    unsigned short hi = f2bf(w);
    unsigned short lo = f2bf(w - bf2f(hi));
    int s = k >> 5, q = (k >> 3) & 3, j = k & 7;
    int idx = (((s * 128 + n) * 4 + q) * 8) + j;
    Whi[idx] = hi;
    Wlo[idx] = lo;
}

// ------ fused preamble: wcast(W1/W2) + zero pooled + per-chunk LDS bucket histogram ------
__global__ __launch_bounds__(256) void k_pre(const float* __restrict__ W1, const float* __restrict__ W2,
                                             unsigned short* __restrict__ w1h, unsigned short* __restrict__ w1l,
                                             unsigned short* __restrict__ w2h, unsigned short* __restrict__ w2l,
                                             const int* __restrict__ dst, int* __restrict__ cnts,
                                             float* __restrict__ pooled) {
    __shared__ int h[NBUCK];
    int b = blockIdx.x, t = threadIdx.x;
    if (b < WC_BLKS) {
        wcast_one(W1, w1h, w1l, b * 256 + t);
    } else if (b < 2 * WC_BLKS) {
        wcast_one(W2, w2h, w2l, (b - WC_BLKS) * 256 + t);
    } else if (b < PRE_H0) {
        pooled[(b - PRE_Z0) * 256 + t] = 0.f;      // G*F = 32768 exactly
    } else {
        int chunk = b - PRE_H0;
        for (int i = t; i < NBUCK; i += 256) h[i] = 0;
        __syncthreads();
        int base = chunk * CHUNK;
        for (int i = t; i < CHUNK; i += 256) {
            int e = base + i;
            if (e < E) atomicAdd(&h[dst[e] >> BSH], 1);   // LDS atomic
        }
        __syncthreads();
        for (int i = t; i < NBUCK; i += 256) cnts[chunk * NBUCK + i] = h[i];
    }
}

// ---- parallel colscan: one block per bucket, in-block scan over NCHUNK=196 values ----
__global__ __launch_bounds__(256) void k_colscan(int* __restrict__ cnts, int* __restrict__ btot) {
    __shared__ int part[256];
    int j = blockIdx.x, t = threadIdx.x;
    int k0 = 2 * t, k1 = 2 * t + 1;
    int v0 = (k0 < NCHUNK) ? cnts[k0 * NBUCK + j] : 0;
    int v1 = (k1 < NCHUNK) ? cnts[k1 * NBUCK + j] : 0;
    int s = v0 + v1;
    part[t] = s;
    __syncthreads();
    for (int off = 1; off < 256; off <<= 1) {
        int u = (t >= off) ? part[t - off] : 0;
        __syncthreads();
        part[t] += u;
        __syncthreads();
    }
    int excl = part[t] - s;
    if (k0 < NCHUNK) cnts[k0 * NBUCK + j] = excl;
    if (k1 < NCHUNK) cnts[k1 * NBUCK + j] = excl + v0;
    if (t == 255) btot[j] = part[255];
}

// ------- fused: layer-1 GEMM (blocks < GB1, direct-reg A) + fillb (blocks >= GB1) -------
// GEMM: A-fragments loaded straight from global x (contiguous 8-float slices per lane),
// no LDS staging, no barrier. fillb rides under the GEMM blocks.
__global__ __launch_bounds__(256) void k_gemmfill(const float* __restrict__ x,
                                                  const unsigned short* __restrict__ w1h,
                                                  const unsigned short* __restrict__ w1l,
                                                  unsigned short* __restrict__ tmp16,
                                                  const int* __restrict__ src,
                                                  const int* __restrict__ dst,
                                                  const int* __restrict__ cnts,
                                                  const int* __restrict__ btot,
                                                  int* __restrict__ bucketbase,
                                                  unsigned int* __restrict__ staging) {
    __shared__ __align__(16) int smem[NBUCK + 1 + 256 + NBUCK];   // 13532 B (fillb only)
    int b = blockIdx.x, t = threadIdx.x;
    if (b < GB1) {
        int wv = t >> 6;
        int lane = t & 63;
        int c16 = lane & 15;
        int q = lane >> 4;
        int arow = b * 64 + wv * 16 + c16;

        // ---- A fragments direct from global: 4 s-steps x 8 contiguous floats ----
        short8 afr[4];
        if (arow < N) {
            const float4* xr = (const float4*)(x + (size_t)arow * 128);
#pragma unroll
            for (int s = 0; s < 4; ++s) {
                float4 v0 = xr[s * 8 + q * 2];
                float4 v1 = xr[s * 8 + q * 2 + 1];
                short8 a;
                a[0] = (short)f2bf(v0.x); a[1] = (short)f2bf(v0.y);
                a[2] = (short)f2bf(v0.z); a[3] = (short)f2bf(v0.w);
                a[4] = (short)f2bf(v1.x); a[5] = (short)f2bf(v1.y);
                a[6] = (short)f2bf(v1.z); a[7] = (short)f2bf(v1.w);
                afr[s] = a;
            }
        } else {
#pragma unroll
            for (int s = 0; s < 4; ++s) afr[s] = (short8){0,0,0,0,0,0,0,0};
        }

        floatx4 acc[8];
#pragma unroll
        for (int nt = 0; nt < 8; ++nt) acc[nt] = (floatx4){0.f, 0.f, 0.f, 0.f};

        const short8* WH = (const short8*)w1h;
        const short8* WL = (const short8*)w1l;
#pragma unroll
        for (int s = 0; s < 4; ++s) {
            int wb = s * 512 + c16 * 4 + q;
#pragma unroll
            for (int nt = 0; nt < 8; ++nt) {
                acc[nt] = __builtin_amdgcn_mfma_f32_16x16x32_bf16(afr[s], WH[wb + nt * 64], acc[nt], 0, 0, 0);
                acc[nt] = __builtin_amdgcn_mfma_f32_16x16x32_bf16(afr[s], WL[wb + nt * 64], acc[nt], 0, 0, 0);
            }
        }

        int rbase = b * 64 + wv * 16 + q * 4;
#pragma unroll
        for (int r = 0; r < 4; ++r) {
            int row = rbase + r;
            if (row < N) {
#pragma unroll
                for (int nt = 0; nt < 8; ++nt)
                    tmp16[row * 128 + nt * 16 + c16] = f2bf(acc[nt][r]);
            }
        }
        return;
    }
    // ---- fillb: deterministic partition into bucket-contiguous staging ----
    int* bb   = smem;                         // NBUCK+1 = 1564
    int* part = bb + (NBUCK + 1);             // 256
    int* lofs = part + 256;                   // NBUCK = 1563
    int chunk = b - GB1;

    // redundant per-block exclusive scan of btot -> bb
    constexpr int CH = (NBUCK + 255) / 256;   // 7
    int beg = t * CH;
    int end = (beg + CH < NBUCK) ? beg + CH : NBUCK;
    int tot[CH];
    int s = 0;
    for (int i = beg; i < end; ++i) {
        tot[i - beg] = btot[i];
        s += btot[i];
    }
    part[t] = s;
    __syncthreads();
    for (int off = 1; off < 256; off <<= 1) {
        int u = (t >= off) ? part[t - off] : 0;
        __syncthreads();
        part[t] += u;
        __syncthreads();
    }
    int run = (t == 0) ? 0 : part[t - 1];
    for (int i = beg; i < end; ++i) {
        bb[i] = run;
        run += tot[i - beg];
    }
    if (t == 255) bb[NBUCK] = part[255];      // == E
    __syncthreads();
    if (chunk == 0)
        for (int i = t; i <= NBUCK; i += 256) bucketbase[i] = bb[i];

    for (int i = t; i < NBUCK; i += 256)
        lofs[i] = bb[i] + cnts[chunk * NBUCK + i];
    __syncthreads();

    int base = chunk * CHUNK;
    for (int i = t; i < CHUNK; i += 256) {
        int e = base + i;
        if (e < E) {
            int d = dst[e];
            int pos = atomicAdd(&lofs[d >> BSH], 1);      // LDS atomic
            staging[pos] = (unsigned int)src[e] | ((unsigned int)(d & (BNODES - 1)) << 16);
        }
    }
}

// ---- pass B: per-bucket counting sort + dinv + in-place pre-scale of tmp16 rows ----
__global__ __launch_bounds__(256) void k_passB(const unsigned int* __restrict__ staging,
                                               const int* __restrict__ bucketbase,
                                               int* __restrict__ csr,
                                               int* __restrict__ rowstart,
                                               float* __restrict__ dinv,
                                               unsigned short* __restrict__ tmp16) {
    __shared__ unsigned int ent[1024];        // mean 512, 11-sigma safe
    __shared__ int h[BNODES * 8], off_a[BNODES * 8];   // (node, slice) bins
    __shared__ int nodebase[BNODES], ndeg[BNODES];
    __shared__ float sdinv[BNODES];
    int b = blockIdx.x, t = threadIdx.x;
    int jb = bucketbase[b], je = bucketbase[b + 1];
    int M = je - jb;
    if (M > 1024) M = 1024;
    if (t < BNODES * 8) h[t] = 0;
    __syncthreads();

    for (int i = t; i < M; i += 256) {
        unsigned int en = staging[jb + i];
        ent[i] = en;
        int key = (((en >> 16) & (BNODES - 1)) << 3) | ((en & 0xFFFFu) >> SSH);
        atomicAdd(&h[key], 1);
    }
    __syncthreads();

    if (t < BNODES) {
        int s = 0;
#pragma unroll
        for (int c = 0; c < 8; ++c) s += h[t * 8 + c];
        ndeg[t] = s;
    }
    __syncthreads();
    if (t == 0) {
        int run = jb;
        for (int k = 0; k < BNODES; ++k) {
            nodebase[k] = run;
            run += ndeg[k];
        }
    }
    __syncthreads();
    if (t < BNODES) {
        int run = nodebase[t];
#pragma unroll
        for (int c = 0; c < 8; ++c) {
            off_a[t * 8 + c] = run;
            run += h[t * 8 + c];
        }
        float dv = rsqrtf((float)(ndeg[t] + 1));   // +1 self-loop
        sdinv[t] = dv;
        int node = b * BNODES + t;
        if (node < N) {
            rowstart[node] = nodebase[t];
            dinv[node] = dv;
        }
    }
    if (b == 0 && t == 0) rowstart[N] = E;
    __syncthreads();

    for (int i = t; i < M; i += 256) {
        unsigned int en = ent[i];
        int key = (((en >> 16) & (BNODES - 1)) << 3) | ((en & 0xFFFFu) >> SSH);
        int loc = atomicAdd(&off_a[key], 1);
        csr[loc] = (int)(en & 0xFFFFu);
    }

    // ---- in-place scale: tmp16[row] *= dinv[row] for this bucket's 32 rows ----
    uint4* t4 = (uint4*)tmp16;
    for (int i = t; i < BNODES * 16; i += 256) {        // 512 uint4, 2 per thread
        int rl = i >> 4, qi = i & 15;
        int node = b * BNODES + rl;
        if (node < N) {
            float dv = sdinv[rl];
            uint4 u = t4[node * 16 + qi];
            uint4 o;
            o.x = pack2bf(bf2f((unsigned short)(u.x & 0xFFFFu)) * dv, bf2f((unsigned short)(u.x >> 16)) * dv);
            o.y = pack2bf(bf2f((unsigned short)(u.y & 0xFFFFu)) * dv, bf2f((unsigned short)(u.y >> 16)) * dv);
            o.z = pack2bf(bf2f((unsigned short)(u.z & 0xFFFFu)) * dv, bf2f((unsigned short)(u.z >> 16)) * dv);
            o.w = pack2bf(bf2f((unsigned short)(u.w & 0xFFFFu)) * dv, bf2f((unsigned short)(u.w >> 16)) * dv);
            t4[node * 16 + qi] = o;
        }
    }
}

// 8 bf16 (uint4) add into 8 fp32 accumulators (coefficient-free hot path)
__device__ inline void add8(const uint4& u, float* acc) {
    union { unsigned int i; float f; } a;
    a.i = u.x << 16;          acc[0] += a.f;
    a.i = u.x & 0xFFFF0000u;  acc[1] += a.f;
    a.i = u.y << 16;          acc[2] += a.f;
    a.i = u.y & 0xFFFF0000u;  acc[3] += a.f;
    a.i = u.z << 16;          acc[4] += a.f;
    a.i = u.z & 0xFFFF0000u;  acc[5] += a.f;
    a.i = u.w << 16;          acc[6] += a.f;
    a.i = u.w & 0xFFFF0000u;  acc[7] += a.f;
}

// 8 bf16 (uint4) fma into 8 fp32 accumulators (masked tail + pooling)
__device__ inline void fma8(const uint4& u, float c, float* acc) {
    union { unsigned int i; float f; } a;
    a.i = u.x << 16;          acc[0] = fmaf(a.f, c, acc[0]);
    a.i = u.x & 0xFFFF0000u;  acc[1] = fmaf(a.f, c, acc[1]);
    a.i = u.y << 16;          acc[2] = fmaf(a.f, c, acc[2]);
    a.i = u.y & 0xFFFF0000u;  acc[3] = fmaf(a.f, c, acc[3]);
    a.i = u.z << 16;          acc[4] = fmaf(a.f, c, acc[4]);
    a.i = u.z & 0xFFFF0000u;  acc[5] = fmaf(a.f, c, acc[5]);
    a.i = u.w << 16;          acc[6] = fmaf(a.f, c, acc[6]);
    a.i = u.w & 0xFFFF0000u;  acc[7] = fmaf(a.f, c, acc[7]);
}

// agg inner loop (round-5 proven form): 8-deep full chunks with next-chunk csr
// prefetch; one masked tail. r6 (16-deep ILP) and r7 (node-split TLP) both
// regressed — the gather is at the memory-system's random-access service limit.
__device__ __forceinline__ void agg_loop(const uint4* __restrict__ t8l,  // t8 + lane
                                         const int* __restrict__ csr,
                                         int jb, int je, float* acc) {
    int n8 = (je - jb) >> 3;
    int j = jb;
    if (n8 > 0) {
        int e[8];
#pragma unroll
        for (int k = 0; k < 8; ++k) e[k] = csr[j + k];
        for (int c = 0; c < n8; ++c) {
            uint4 u[8];
#pragma unroll
            for (int k = 0; k < 8; ++k) u[k] = t8l[e[k] * 16];
            j += 8;
            if (c + 1 < n8) {
#pragma unroll
                for (int k = 0; k < 8; ++k) e[k] = csr[j + k];   // prefetch next chunk's indices
            }
#pragma unroll
            for (int k = 0; k < 8; ++k) add8(u[k], acc);
        }
    }
    if (j < je) {                       // masked tail (1..7 edges)
        int e[8];
        float msk[8];
#pragma unroll
        for (int k = 0; k < 8; ++k) {
            int idx = j + k;
            e[k] = csr[idx < je ? idx : je - 1];
            msk[k] = (idx < je) ? 1.0f : 0.0f;
        }
        uint4 u[8];
#pragma unroll
        for (int k = 0; k < 8; ++k) u[k] = t8l[e[k] * 16];
#pragma unroll
        for (int k = 0; k < 8; ++k) fma8(u[k], msk[k], acc);
    }
}

// ---------------- fused layer-1 agg + layer-2 GEMM (16 nodes/block) ----------------
__global__ __launch_bounds__(256) void k_agg1gemm(const unsigned short* __restrict__ tmp16,
                                                  const int* __restrict__ csr,
                                                  const int* __restrict__ rowstart,
                                                  const float* __restrict__ dinv,
                                                  const float* __restrict__ bias,
                                                  const unsigned short* __restrict__ w2h,
                                                  const unsigned short* __restrict__ w2l,
                                                  unsigned short* __restrict__ tmp2) {
    __shared__ __align__(16) unsigned short Albs[16 * 136];
    int tid = threadIdx.x;
    int row0 = blockIdx.x * 16;

    // ---- phase A: aggregation (h1 = relu(dinv_d * sum(tmp16[s]) + b1); tmp16 pre-scaled) ----
    {
        int node = row0 + (tid >> 4);
        int lane = tid & 15;
        const uint4* t8l = (const uint4*)tmp16 + lane;
        float acc[8] = {0.f, 0.f, 0.f, 0.f, 0.f, 0.f, 0.f, 0.f};
        add8(t8l[node * 16], acc);                       // self-loop term
        agg_loop(t8l, csr, rowstart[node], rowstart[node + 1], acc);

        float di = dinv[node];
        const float4* b4 = (const float4*)bias;
        float4 ba = b4[lane * 2], bb = b4[lane * 2 + 1];
        uint4 o;
        o.x = pack2bf(fmaxf(fmaf(acc[0], di, ba.x), 0.f), fmaxf(fmaf(acc[1], di, ba.y), 0.f));
        o.y = pack2bf(fmaxf(fmaf(acc[2], di, ba.z), 0.f), fmaxf(fmaf(acc[3], di, ba.w), 0.f));
        o.z = pack2bf(fmaxf(fmaf(acc[4], di, bb.x), 0.f), fmaxf(fmaf(acc[5], di, bb.y), 0.f));
        o.w = pack2bf(fmaxf(fmaf(acc[6], di, bb.z), 0.f), fmaxf(fmaf(acc[7], di, bb.w), 0.f));
        *(uint4*)&Albs[(tid >> 4) * 136 + lane * 8] = o;
    }
    __syncthreads();

    // ---- phase B: 16-row MFMA gemm, 4 waves x 2 n-tiles; output pre-scaled by dinv ----
    int wv = tid >> 6;
    int lane = tid & 63;
    int c16 = lane & 15;
    int q = lane >> 4;

    floatx4 acc[2];
    acc[0] = (floatx4){0.f, 0.f, 0.f, 0.f};
    acc[1] = (floatx4){0.f, 0.f, 0.f, 0.f};

    const short8* WH = (const short8*)w2h;
    const short8* WL = (const short8*)w2l;
#pragma unroll
    for (int s = 0; s < 4; ++s) {
        short8 a = *(const short8*)&Albs[c16 * 136 + s * 32 + q * 8];
        int wb = s * 512 + c16 * 4 + q;
#pragma unroll
        for (int i = 0; i < 2; ++i) {
            int nt = wv * 2 + i;
            acc[i] = __builtin_amdgcn_mfma_f32_16x16x32_bf16(a, WH[wb + nt * 64], acc[i], 0, 0, 0);
            acc[i] = __builtin_amdgcn_mfma_f32_16x16x32_bf16(a, WL[wb + nt * 64], acc[i], 0, 0, 0);
        }
    }

    int rbase = row0 + q * 4;
#pragma unroll
    for (int r = 0; r < 4; ++r) {
        int row = rbase + r;
        float dv = dinv[row];
#pragma unroll
        for (int i = 0; i < 2; ++i) {
            int nt = wv * 2 + i;
            tmp2[row * 128 + nt * 16 + c16] = f2bf(acc[i][r] * dv);
        }
    }
}

// ------- layer-2 aggregation + fused pooling (batch sorted -> LDS run-reduce + atomics) -------
__global__ __launch_bounds__(256) void k_agg(const unsigned short* __restrict__ tmp16,
                                             const int* __restrict__ csr,
                                             const int* __restrict__ rowstart,
                                             const float* __restrict__ dinv,
                                             const float* __restrict__ bias,
                                             const int* __restrict__ batch,
                                             float* __restrict__ pooled) {
    __shared__ float red[16][128];
    __shared__ int gid[16];
    int tid = threadIdx.x;
    int node0 = blockIdx.x * 16;              // AGB*16 == N exactly
    int ns = tid >> 4, lane = tid & 15;
    int node = node0 + ns;
    const uint4* t8l = (const uint4*)tmp16 + lane;
    float acc[8] = {0.f, 0.f, 0.f, 0.f, 0.f, 0.f, 0.f, 0.f};
    add8(t8l[node * 16], acc);
    agg_loop(t8l, csr, rowstart[node], rowstart[node + 1], acc);

    float di = dinv[node];
    const float4* b4 = (const float4*)bias;
    float4 ba = b4[lane * 2], bb = b4[lane * 2 + 1];
    red[ns][lane * 8 + 0] = fmaxf(fmaf(acc[0], di, ba.x), 0.f);
    red[ns][lane * 8 + 1] = fmaxf(fmaf(acc[1], di, ba.y), 0.f);
    red[ns][lane * 8 + 2] = fmaxf(fmaf(acc[2], di, ba.z), 0.f);
    red[ns][lane * 8 + 3] = fmaxf(fmaf(acc[3], di, ba.w), 0.f);
    red[ns][lane * 8 + 4] = fmaxf(fmaf(acc[4], di, bb.x), 0.f);
    red[ns][lane * 8 + 5] = fmaxf(fmaf(acc[5], di, bb.y), 0.f);
    red[ns][lane * 8 + 6] = fmaxf(fmaf(acc[6], di, bb.z), 0.f);
    red[ns][lane * 8 + 7] = fmaxf(fmaf(acc[7], di, bb.w), 0.f);
    if (tid < 16) gid[tid] = batch[node0 + tid];
    __syncthreads();

    if (tid < 128) {
        int f = tid;
        float run = 0.f;
        int g = gid[0];
        for (int r = 0; r < 16; ++r) {
            if (gid[r] != g) {
                atomicAdd(&pooled[g * 128 + f], run);
                run = 0.f;
                g = gid[r];
            }
            run += red[r][f];
        }
        atomicAdd(&pooled[g * 128 + f], run);
    }
}

// ---------------- slim pool-finish + fc + head: reads pooled sums only ----------------
__global__ __launch_bounds__(128) void k_poolhead(const float* __restrict__ pooled,
                                                  const int* __restrict__ batch,
                                                  const float* __restrict__ Wfc,
                                                  const float* __restrict__ bfc,
                                                  const float* __restrict__ Wh,
                                                  const float* __restrict__ bh,
                                                  float* __restrict__ out) {
    __shared__ float p[128];
    __shared__ float zs[128];
    int g = blockIdx.x, t = threadIdx.x;

    int lo = 0, hi = N;                       // lower_bound(g)
    while (lo < hi) { int m = (lo + hi) >> 1; if (batch[m] < g) lo = m + 1; else hi = m; }
    int lo1 = lo, hi1 = N;                    // lower_bound(g+1)
    while (lo1 < hi1) { int m = (lo1 + hi1) >> 1; if (batch[m] < g + 1) lo1 = m + 1; else hi1 = m; }
    int cnt = lo1 - lo;
    float inv = 1.0f / (float)((cnt > 1) ? cnt : 1);

    p[t] = pooled[g * 128 + t] * inv;
    __syncthreads();

    float a = bfc[t];
    for (int k = 0; k < F; ++k) a = fmaf(p[k], Wfc[k * F + t], a);
    zs[t] = fmaxf(a, 0.f);
    __syncthreads();

    if (t < T * 2) {
        int task = t >> 1, c = t & 1;
        float a2 = bh[task * 2 + c];
        const float* wr = &Wh[task * F * 2 + c];
        for (int h = 0; h < F; ++h) a2 = fmaf(zs[h], wr[h * 2], a2);
        out[task * (G * 2) + g * 2 + c] = a2;
    }
}

extern "C" void kernel_launch(void* const* d_in, const int* in_sizes, int n_in,
                              void* d_out, int out_size, void* d_ws, size_t ws_size,
                              hipStream_t stream) {
    const float* x    = (const float*)d_in[0];
    const int*   ei   = (const int*)d_in[1];      // [2,E]: row0=src, row1=dst
    const int*   batch= (const int*)d_in[2];
    const float* W1   = (const float*)d_in[3];
    const float* b1   = (const float*)d_in[4];
    const float* W2   = (const float*)d_in[5];
    const float* b2   = (const float*)d_in[6];
    const float* Wfc  = (const float*)d_in[7];
    const float* bfc  = (const float*)d_in[8];
    const float* Wh   = (const float*)d_in[9];
    const float* bh   = (const float*)d_in[10];
    float* out = (float*)d_out;

    const int* srcp = ei;
    const int* dstp = ei + E;

    char* w = (char*)d_ws;
    auto alloc = [&](size_t bytes) {
        char* p = w;
        w += (bytes + 255) & ~(size_t)255;
        return p;
    };
    unsigned short* tmp16 = (unsigned short*)alloc((size_t)N * F * 2);
    unsigned short* tmp2  = (unsigned short*)alloc((size_t)N * F * 2);
    int*   csr      = (int*)  alloc((size_t)E * 4);
    unsigned int* staging = (unsigned int*)alloc((size_t)E * 4);
    int*   cnts     = (int*)  alloc((size_t)NCHUNK * NBUCK * 4);
    int*   btot     = (int*)  alloc((size_t)NBUCK * 4);
    int*   bucketbase=(int*)  alloc((size_t)(NBUCK + 1) * 4);
    int*   rowstart = (int*)  alloc((size_t)(N + 1) * 4);
    float* dinv     = (float*)alloc((size_t)N * 4);
    float* pooled   = (float*)alloc((size_t)G * F * 4);
    unsigned short* w1h = (unsigned short*)alloc((size_t)F * F * 2);
    unsigned short* w1l = (unsigned short*)alloc((size_t)F * F * 2);
    unsigned short* w2h = (unsigned short*)alloc((size_t)F * F * 2);
    unsigned short* w2l = (unsigned short*)alloc((size_t)F * F * 2);

    // fused preamble: wcast W1/W2 + zero pooled + per-chunk LDS bucket histogram
    k_pre<<<PRE_BLKS, 256, 0, stream>>>(W1, W2, w1h, w1l, w2h, w2l, dstp, cnts, pooled);

    // parallel colscan (tiny): cnts -> within-bucket offsets + btot
    k_colscan<<<NBUCK, 256, 0, stream>>>(cnts, btot);

    // fused: layer-1 GEMM (direct-reg A, no LDS) + fillb partition (hidden under GEMM)
    k_gemmfill<<<GFB, 256, 0, stream>>>(x, w1h, w1l, tmp16, srcp, dstp, cnts, btot,
                                        bucketbase, staging);

    // passB: counting sort + dinv + in-place pre-scale of tmp16
    k_passB<<<NBUCK, 256, 0, stream>>>(staging, bucketbase, csr, rowstart, dinv, tmp16);

    // fused: layer-1 aggregation (coefficient-free gather) + layer-2 GEMM
    k_agg1gemm<<<AGB, 256, 0, stream>>>(tmp16, csr, rowstart, dinv, b1, w2h, w2l, tmp2);

    // layer-2 aggregation + fused pooling (atomics into pooled)
    k_agg<<<AGB, 256, 0, stream>>>(tmp2, csr, rowstart, dinv, b2, batch, pooled);

    // slim pool-finish + fc + head
    k_poolhead<<<G, 128, 0, stream>>>(pooled, batch, Wfc, bfc, Wh, bh, out);
}